// Round 6
// baseline (307.396 us; speedup 1.0000x reference)
//
#include <hip/hip_runtime.h>
#include <hip/hip_bf16.h>
#include <math.h>

#define DEV __device__ __forceinline__

typedef short short8 __attribute__((ext_vector_type(8)));
typedef float f32x4  __attribute__((ext_vector_type(4)));

DEV float sigf(float x)   { return 1.0f / (1.0f + __expf(-x)); }
DEV float tanhft(float x) { return 1.0f - 2.0f / (__expf(2.0f * x) + 1.0f); }

// float -> bf16 (round to nearest even), as raw u16
DEV unsigned short f2bf(float f) {
    unsigned int u = __float_as_uint(f);
    unsigned int r = (u + 0x7FFFu + ((u >> 16) & 1u)) >> 16;
    return (unsigned short)r;
}
DEV float bf2f(unsigned short u) {
    return __uint_as_float(((unsigned int)u) << 16);
}

// LDS-only barrier: drain LDS ops but leave global loads (vmcnt) in flight.
DEV void bar_lds() {
    asm volatile("s_waitcnt lgkmcnt(0)" ::: "memory");
    __builtin_amdgcn_s_barrier();
}

// ---------------------------------------------------------------------------
// prep_all = prep (blocks 0..257) + prep_iw1 (blocks 258..2785). One launch.
// ---------------------------------------------------------------------------
__global__ __launch_bounds__(256) void prep_all_kernel(
    const float* __restrict__ w_hh0, const float* __restrict__ w_ih1,
    const float* __restrict__ w_hh1,
    const float* __restrict__ b_ih0, const float* __restrict__ b_hh0,
    const float* __restrict__ b_ih1, const float* __restrict__ b_hh1,
    const float* __restrict__ iw1,
    unsigned short* __restrict__ whh0h, unsigned short* __restrict__ wih1h,
    unsigned short* __restrict__ whh1h,
    float* __restrict__ bias0, float* __restrict__ bias1,
    unsigned short* __restrict__ iw1b)
{
    int blk = blockIdx.x;
    if (blk < 258) {
        int i = blk * 256 + threadIdx.x;
        if (i < 65536) {
            whh0h[i] = f2bf(w_hh0[i]);
            wih1h[i] = f2bf(w_ih1[i]);
            whh1h[i] = f2bf(w_hh1[i]);
        } else if (i < 66048) {
            int c = i - 65536;
            bias0[c] = b_ih0[c] + b_hh0[c];
            bias1[c] = b_ih1[c] + b_hh1[c];
        }
    } else {
        int i = (blk - 258) * 256 + threadIdx.x;
        if (i < 256 * 2528) {
            int row = i / 2528, k = i - row * 2528;
            iw1b[i] = (k < 2500) ? f2bf(iw1[row * 2500 + k]) : (unsigned short)0;
        }
    }
}

// ---------------------------------------------------------------------------
// MFMA LSTM — R4-verified main loop (131 us) UNCHANGED. Epilogue now fuses
// phase2: base = tanh(relu(h2@pw1^T+pb1)@pw2^T+pb2), computed from the hl
// each lane already holds. h2 never round-trips to HBM; phase2 launch gone.
// LDS adds pw1s/pw2s/p1l (~42 KB): total ~83 KB, still 1 block/CU (grid=256).
// ---------------------------------------------------------------------------
__global__ __launch_bounds__(512, 2) void lstm_kernel(
    const float* __restrict__ x,
    const unsigned short* __restrict__ whh0,
    const unsigned short* __restrict__ wih1,
    const unsigned short* __restrict__ whh1,
    const float* __restrict__ wih0,
    const float* __restrict__ bias0, const float* __restrict__ bias1,
    const float* __restrict__ pw1, const float* __restrict__ pb1,
    const float* __restrict__ pw2, const float* __restrict__ pb2,
    float* __restrict__ base)
{
    __shared__ __align__(16) float          xs[4][304];
    __shared__ __align__(16) unsigned short h0s[2][16][136];
    __shared__ __align__(16) unsigned short h1s[2][16][136];
    __shared__ __align__(16) float          wsc[8][4][16][4]; // [wave][g][col][row]
    __shared__ float wih0s[2560];
    __shared__ float pw1s[64 * 129];
    __shared__ float pw2s[32 * 65];
    __shared__ float p1l[256];

    const int tid = threadIdx.x;
    const int b0  = blockIdx.x * 4;
    const int l15 = tid & 15;          // MFMA A-row / C-col lane index
    const int q   = (tid >> 4) & 3;    // lane quad == owned batch row
    const int w   = tid >> 6;          // wave 0..7
    const int j   = w * 16 + l15;      // owned hidden unit 0..127
    const int q8  = q * 8;

    // ---- stage x (4 rows), w_ih0; zero h buffers (rows 4..15 stay zero)
    for (int i = tid; i < 1200; i += 512) {
        int m = i / 300, kk = i - m * 300;
        xs[m][kk] = x[(b0 + m) * 300 + kk];
    }
    for (int i = tid; i < 2560; i += 512) wih0s[i] = wih0[i];
    for (int i = tid; i < 2176; i += 512) {
        ((unsigned int*)h0s)[i] = 0u;
        ((unsigned int*)h1s)[i] = 0u;
    }

    // ---- per-lane biases for unit j (loop-invariant, 8 regs)
    float ub0[4], ub1[4];
#pragma unroll
    for (int g = 0; g < 4; ++g) {
        ub0[g] = bias0[g * 128 + j];
        ub1[g] = bias1[g * 128 + j];
    }

    // ---- resident B-fragments: w_hh0, w_ih1 (w_hh1 is streamed)
    short8 bh0[4][4], b1i[4][4];
#pragma unroll
    for (int g = 0; g < 4; ++g)
#pragma unroll
        for (int kc = 0; kc < 4; ++kc) {
            int off = (g * 128 + j) * 128 + kc * 32 + q8;
            bh0[g][kc] = *(const short8*)(whh0 + off);
            b1i[g][kc] = *(const short8*)(wih1 + off);
        }

    float c0 = 0.f, c1 = 0.f, hl = 0.f;
    __syncthreads();

    const unsigned short* wsb = whh1 + j * 128 + q8;  // per-lane stream base

    for (int t = 0; t < 60; ++t) {
        const int p = t & 1;

        // ---- prefetch streamed w_hh1, first half (in flight across BAR)
        short8 wsv[4][4];
#pragma unroll
        for (int g = 0; g < 4; ++g) {
            wsv[g][0] = *(const short8*)(wsb + g * 16384);
            wsv[g][1] = *(const short8*)(wsb + g * 16384 + 32);
        }

        // ================= phase A: layer 0 =================
        f32x4 acc[4];
#pragma unroll
        for (int g = 0; g < 4; ++g) acc[g] = (f32x4){0.f, 0.f, 0.f, 0.f};
        short8 af[4];
#pragma unroll
        for (int kc = 0; kc < 4; ++kc)
            af[kc] = *(const short8*)&h0s[p][l15][kc * 32 + q8];
#pragma unroll
        for (int kc = 0; kc < 4; ++kc)
#pragma unroll
            for (int g = 0; g < 4; ++g)
                acc[g] = __builtin_amdgcn_mfma_f32_16x16x32_bf16(af[kc], bh0[g][kc], acc[g], 0, 0, 0);

        // ---- prefetch streamed w_hh1, second half
#pragma unroll
        for (int g = 0; g < 4; ++g) {
            wsv[g][2] = *(const short8*)(wsb + g * 16384 + 64);
            wsv[g][3] = *(const short8*)(wsb + g * 16384 + 96);
        }

        // intra-wave redistribute: q==0 lanes publish rows 0..3 of 16 cols
        if (q == 0) {
#pragma unroll
            for (int g = 0; g < 4; ++g)
                *(f32x4*)&wsc[w][g][l15][0] = acc[g];
        }
        // each lane picks up (row=q, unit=j); lgkmcnt orders intra-wave
        {
            const float* xr = &xs[q][t * 5];
            float x0 = xr[0], x1 = xr[1], x2 = xr[2], x3 = xr[3], x4 = xr[4];
            float gv[4];
#pragma unroll
            for (int g = 0; g < 4; ++g) {
                const float* wr = &wih0s[(g * 128 + j) * 5];
                float s = wsc[w][g][l15][q] + ub0[g];
                s = fmaf(x0, wr[0], s);
                s = fmaf(x1, wr[1], s);
                s = fmaf(x2, wr[2], s);
                s = fmaf(x3, wr[3], s);
                gv[g] = fmaf(x4, wr[4], s);
            }
            c0 = sigf(gv[1]) * c0 + sigf(gv[0]) * tanhft(gv[2]);
            float h = sigf(gv[3]) * tanhft(c0);
            h0s[1 - p][q][j] = f2bf(h);
        }

        bar_lds();  // the ONLY barrier per step

        // ================= phase B: layer 1 =================
#pragma unroll
        for (int g = 0; g < 4; ++g) acc[g] = (f32x4){0.f, 0.f, 0.f, 0.f};
#pragma unroll
        for (int kc = 0; kc < 4; ++kc)
            af[kc] = *(const short8*)&h0s[1 - p][l15][kc * 32 + q8];
#pragma unroll
        for (int kc = 0; kc < 4; ++kc)
#pragma unroll
            for (int g = 0; g < 4; ++g)
                acc[g] = __builtin_amdgcn_mfma_f32_16x16x32_bf16(af[kc], b1i[g][kc], acc[g], 0, 0, 0);
#pragma unroll
        for (int kc = 0; kc < 4; ++kc)
            af[kc] = *(const short8*)&h1s[p][l15][kc * 32 + q8];
#pragma unroll
        for (int kc = 0; kc < 4; ++kc)
#pragma unroll
            for (int g = 0; g < 4; ++g)
                acc[g] = __builtin_amdgcn_mfma_f32_16x16x32_bf16(af[kc], wsv[g][kc], acc[g], 0, 0, 0);

        if (q == 0) {
#pragma unroll
            for (int g = 0; g < 4; ++g)
                *(f32x4*)&wsc[w][g][l15][0] = acc[g];
        }
        {
            float gv[4];
#pragma unroll
            for (int g = 0; g < 4; ++g)
                gv[g] = wsc[w][g][l15][q] + ub1[g];
            c1 = sigf(gv[1]) * c1 + sigf(gv[0]) * tanhft(gv[2]);
            float h = sigf(gv[3]) * tanhft(c1);
            h1s[1 - p][q][j] = f2bf(h);
            hl = h;
        }
        // no barrier: next step's bar_lds covers h1/h0/wsc hazards
    }

    // ================= fused phase2 epilogue =================
    // stage pw1/pw2 coalesced (fresh LDS region; no hazard with wsc reads)
    for (int i = tid; i < 8192; i += 512)
        pw1s[(i >> 7) * 129 + (i & 127)] = pw1[i];
    for (int i = tid; i < 2048; i += 512)
        pw2s[(i >> 6) * 65 + (i & 63)] = pw2[i];
    bar_lds();   // all waves past final wsc reads; staging ordered
    float* h2l = (float*)wsc;        // reuse wsc region: h2 rows [4][128]
    h2l[q * 128 + j] = hl;
    bar_lds();   // h2l + pw1s/pw2s visible
    if (tid < 256) {
        const int r = tid >> 6, u = tid & 63;
        float acc = pb1[u];
        const float* wr = &pw1s[u * 129];
        const float* hr = &h2l[r * 128];
#pragma unroll 4
        for (int k = 0; k < 128; ++k) acc = fmaf(hr[k], wr[k], acc);
        p1l[r * 64 + u] = fmaxf(acc, 0.f);
    }
    bar_lds();
    if (tid < 128) {
        const int r = tid >> 5, u2 = tid & 31;
        float a2 = pb2[u2];
        const float* wr = &pw2s[u2 * 65];
        const float* pr = &p1l[r * 64];
#pragma unroll 4
        for (int k = 0; k < 64; ++k) a2 = fmaf(pr[k], wr[k], a2);
        base[(b0 + r) * 32 + u2] = tanhft(a2);
    }
}

// ---------------------------------------------------------------------------
// weff v2: stage conn_idx/conn_w into LDS coalesced (pad-51 layout,
// conflict-free per-thread reads), then scatter. Replaces lane-stride-200B
// uncoalesced global reads (latency chain on only 20 blocks).
// W_eff^T[j][n] = sum_{k: conn_idx[n,k]%32==j} conn_w[n,k]
// ---------------------------------------------------------------------------
__global__ __launch_bounds__(128) void weff_kernel(
    const int* __restrict__ conn_idx, const float* __restrict__ conn_w,
    float* __restrict__ weffT)
{
    __shared__ int   idxp[128 * 51];
    __shared__ float wp[128 * 51];
    __shared__ float s[128 * 33];
    const int tid = threadIdx.x;
    const int nb  = blockIdx.x * 128;
    const int gbase = nb * 50;
    for (int i = tid; i < 6400; i += 128) {
        int r = i / 50, c = i - r * 50;
        bool v = (nb + r) < 2500;
        idxp[r * 51 + c] = v ? conn_idx[gbase + i] : 0;
        wp[r * 51 + c]   = v ? conn_w[gbase + i]   : 0.f;
    }
    float* sr = &s[tid * 33];
#pragma unroll
    for (int jj = 0; jj < 32; ++jj) sr[jj] = 0.f;
    __syncthreads();
    int n = nb + tid;
    if (n < 2500) {
        for (int k = 0; k < 50; ++k) {
            int idx = idxp[tid * 51 + k];
            sr[idx & 31] += wp[tid * 51 + k];
        }
        for (int jj = 0; jj < 32; ++jj) weffT[jj * 2500 + n] = sr[jj];
    }
}

// ---------------------------------------------------------------------------
// z = (base @ W_eff^T)*sens; a = per-group activation. amat stored bf16
// [b][2528] (K-padded with zeros for the MFMA GEMM).
// ---------------------------------------------------------------------------
__global__ __launch_bounds__(256) void za_kernel(
    const float* __restrict__ base, const float* __restrict__ weffT,
    const float* __restrict__ sens, const float* __restrict__ thr,
    unsigned short* __restrict__ amat)
{
    __shared__ float bs[16][32];
    int tid = threadIdx.x;
    int bb = blockIdx.x / 10, nb = blockIdx.x % 10;
    int n = nb * 256 + tid;
    bool nv = n < 2500;
    bool pv = n < 2528;
    int nn = nv ? n : 0;
    for (int i = tid; i < 512; i += 256) bs[i >> 5][i & 31] = base[bb * 512 + i];
    __syncthreads();
    float w[32];
#pragma unroll
    for (int j = 0; j < 32; ++j) w[j] = weffT[j * 2500 + nn];
    float sn = sens[nn], tn = thr[nn];
    int g = (n < 800) ? 0 : (n < 1500) ? 1 : (n < 2100) ? 2 : 3;
#pragma unroll 2
    for (int r = 0; r < 16; ++r) {
        float z = 0.f;
#pragma unroll
        for (int j = 0; j < 32; ++j) z = fmaf(bs[r][j], w[j], z);
        z *= sn;
        float av;
        if (g == 0)      av = sigf(z - tn);
        else if (g == 1) av = tanhft(z);
        else if (g == 2) av = fmaxf(z - tn, 0.f);
        else             av = sigf(z);
        if (nv)      amat[(bb * 16 + r) * 2528 + n] = f2bf(av);
        else if (pv) amat[(bb * 16 + r) * 2528 + n] = 0;
    }
}

// ---------------------------------------------------------------------------
// t1 = relu(a @ iw1^T + ib1): M=1024 N=256 K=2528(padded), bf16 MFMA.
// v3: 4-deep software pipeline (12 loads in flight/wave, static slot
// indices via hand-unrolled body) — the 1-deep version serialized ~79
// L2/L3-latency stalls per wave. Grid (8,32)=256 blocks x 128 thr.
// ---------------------------------------------------------------------------
__global__ __launch_bounds__(128) void gemm_iw1_kernel(
    const unsigned short* __restrict__ ab, const unsigned short* __restrict__ wb,
    const float* __restrict__ ib1, float* __restrict__ t1)
{
    const int tid = threadIdx.x;
    const int wv  = tid >> 6;
    const int l15 = tid & 15, q = (tid >> 4) & 3, q8 = q * 8;
    const int row0 = blockIdx.y * 32 + wv * 16;
    const int col0 = blockIdx.x * 32;

    const unsigned short* A = ab + (row0 + l15) * 2528 + q8;
    const unsigned short* B = wb + (col0 + l15) * 2528 + q8;

    short8 a[4], b0v[4], b1v[4];
#pragma unroll
    for (int u = 0; u < 4; ++u) {
        a[u]   = *(const short8*)(A + u * 32);
        b0v[u] = *(const short8*)(B + u * 32);
        b1v[u] = *(const short8*)(B + 16 * 2528 + u * 32);
    }

    f32x4 acc0 = (f32x4){0.f, 0.f, 0.f, 0.f};
    f32x4 acc1 = (f32x4){0.f, 0.f, 0.f, 0.f};

    for (int c4 = 0; c4 < 72; c4 += 4) {
#pragma unroll
        for (int u = 0; u < 4; ++u) {           // u static -> regs, no scratch
            short8 av = a[u], bv0 = b0v[u], bv1 = b1v[u];
            int cn = c4 + u + 4;                 // max 75: in-bounds
            a[u]   = *(const short8*)(A + cn * 32);
            b0v[u] = *(const short8*)(B + cn * 32);
            b1v[u] = *(const short8*)(B + 16 * 2528 + cn * 32);
            acc0 = __builtin_amdgcn_mfma_f32_16x16x32_bf16(av, bv0, acc0, 0, 0, 0);
            acc1 = __builtin_amdgcn_mfma_f32_16x16x32_bf16(av, bv1, acc1, 0, 0, 0);
        }
    }
    // slots hold c=72..75; process, loading c=76..78 (u<3 static guard)
#pragma unroll
    for (int u = 0; u < 4; ++u) {
        short8 av = a[u], bv0 = b0v[u], bv1 = b1v[u];
        if (u < 3) {
            int cn = 76 + u;                     // 78*32+24+8 = 2528: in-bounds
            a[u]   = *(const short8*)(A + cn * 32);
            b0v[u] = *(const short8*)(B + cn * 32);
            b1v[u] = *(const short8*)(B + 16 * 2528 + cn * 32);
        }
        acc0 = __builtin_amdgcn_mfma_f32_16x16x32_bf16(av, bv0, acc0, 0, 0, 0);
        acc1 = __builtin_amdgcn_mfma_f32_16x16x32_bf16(av, bv1, acc1, 0, 0, 0);
    }
#pragma unroll
    for (int u = 0; u < 3; ++u) {               // c=76..78
        acc0 = __builtin_amdgcn_mfma_f32_16x16x32_bf16(a[u], b0v[u], acc0, 0, 0, 0);
        acc1 = __builtin_amdgcn_mfma_f32_16x16x32_bf16(a[u], b1v[u], acc1, 0, 0, 0);
    }

    {
        int n = col0 + l15;
        float bias = ib1[n];
#pragma unroll
        for (int i = 0; i < 4; ++i) {
            int row = row0 + q * 4 + i;
            t1[row * 256 + n] = fmaxf(acc0[i] + bias, 0.f);
        }
        n = col0 + 16 + l15;
        bias = ib1[n];
#pragma unroll
        for (int i = 0; i < 4; ++i) {
            int row = row0 + q * 4 + i;
            t1[row * 256 + n] = fmaxf(acc1[i] + bias, 0.f);
        }
    }
}

// ---------------------------------------------------------------------------
// final v3 = final v2 + fused group-means (wave w owns batch row w: clean
// unmasked shuffle reduce over its amat row). means_kernel launch deleted.
// ---------------------------------------------------------------------------
__global__ __launch_bounds__(256) void final_kernel(
    const float* __restrict__ t1, const unsigned short* __restrict__ amat,
    const float* __restrict__ iw2,
    const float* __restrict__ ib2, const float* __restrict__ iw3,
    const float* __restrict__ ib3,
    const float* __restrict__ hw_trend, const float* __restrict__ hb_trend,
    const float* __restrict__ hw_pat,   const float* __restrict__ hb_pat,
    const float* __restrict__ hw_key,   const float* __restrict__ hb_key,
    const float* __restrict__ hw_vol,   const float* __restrict__ hb_vol,
    const float* __restrict__ hw_conf,  const float* __restrict__ hb_conf,
    float* __restrict__ out)
{
    __shared__ float iw2s[64 * 257];
    __shared__ float iw3s[32 * 65];
    __shared__ float t1s[4][256];
    __shared__ float t2s[4][64];
    __shared__ float igs[4][32];
    __shared__ float mred[4][4];

    const int tid = threadIdx.x;
    const int b0  = blockIdx.x * 4;

    for (int i = tid; i < 16384; i += 256) {
        int u = i >> 8, k = i & 255;
        iw2s[u * 257 + k] = iw2[i];
    }
    for (int i = tid; i < 2048; i += 256) {
        int u = i >> 6, k = i & 63;
        iw3s[u * 65 + k] = iw3[i];
    }
    for (int i = tid; i < 1024; i += 256)
        t1s[i >> 8][i & 255] = t1[b0 * 256 + i];

    // ---- fused means: wave wv4 scans amat row b0+wv4 (316 short8 chunks)
    {
        const int lane = tid & 63, wv4 = tid >> 6;
        const unsigned short* arow = amat + (unsigned int)(b0 + wv4) * 2528;
        float parts[4] = {0.f, 0.f, 0.f, 0.f};
#pragma unroll
        for (int s = 0; s < 5; ++s) {
            int c = lane + 64 * s;
            if (c < 316) {
                short8 v = *(const short8*)(arow + c * 8);
#pragma unroll
                for (int e = 0; e < 8; ++e) {
                    int n = c * 8 + e;
                    float f = bf2f((unsigned short)v[e]);
                    if (n < 800)       parts[0] += f;
                    else if (n < 1500) parts[1] += f;
                    else if (n < 2100) parts[2] += f;
                    else               parts[3] += f;  // pad region adds 0
                }
            }
        }
#pragma unroll
        for (int g = 0; g < 4; ++g) {
            float v = parts[g];
            for (int s2 = 32; s2 > 0; s2 >>= 1) v += __shfl_down(v, s2, 64);
            if (lane == 0) mred[wv4][g] = v;
        }
    }
    __syncthreads();

    {
        const int r = tid >> 6, u = tid & 63;
        float acc = ib2[u];
        const float* wr = &iw2s[u * 257];
        const float* tr = &t1s[r][0];
#pragma unroll 4
        for (int k = 0; k < 256; ++k) acc = fmaf(tr[k], wr[k], acc);
        t2s[r][u] = fmaxf(acc, 0.f);
    }
    __syncthreads();

    if (tid < 128) {
        const int r = tid >> 5, u2 = tid & 31;
        float a2 = ib3[u2];
        const float* wr = &iw3s[u2 * 65];
        const float* tr = &t2s[r][0];
#pragma unroll 4
        for (int k = 0; k < 64; ++k) a2 = fmaf(tr[k], wr[k], a2);
        igs[r][u2] = tanhft(a2);
    }
    __syncthreads();

    if (tid < 60) {
        const int r = tid / 15, t15 = tid % 15;
        const int b = b0 + r;
        const float* w; const float* bb; int j, off;
        if (t15 < 3)        { w = hw_trend; bb = hb_trend; j = t15;     off = 0; }
        else if (t15 < 9)   { w = hw_pat;   bb = hb_pat;   j = t15 - 3; off = 3; }
        else if (t15 < 13)  { w = hw_key;   bb = hb_key;   j = t15 - 9; off = 9; }
        else if (t15 == 13) { w = hw_vol;   bb = hb_vol;   j = 0;       off = 13; }
        else                { w = hw_conf;  bb = hb_conf;  j = 0;       off = 14; }
        float a3 = bb[j];
#pragma unroll
        for (int k = 0; k < 32; ++k) a3 = fmaf(igs[r][k], w[j * 32 + k], a3);
        out[b * 20 + off + j] = a3;
        if (t15 == 14) out[b * 20 + 15] = sigf(a3);
    }
    if (tid < 16) {
        const int r = tid >> 2, g = tid & 3;
        const float inv[4] = {1.f / 800.f, 1.f / 700.f, 1.f / 600.f, 1.f / 400.f};
        out[(b0 + r) * 20 + 16 + g] = mred[r][g] * inv[g];
    }
}

// ---------------------------------------------------------------------------
extern "C" void kernel_launch(void* const* d_in, const int* in_sizes, int n_in,
                              void* d_out, int out_size, void* d_ws, size_t ws_size,
                              hipStream_t stream)
{
    const float* x        = (const float*)d_in[0];
    const int*   conn_idx = (const int*)  d_in[1];
    const float* w_ih0    = (const float*)d_in[2];
    const float* w_hh0    = (const float*)d_in[3];
    const float* b_ih0    = (const float*)d_in[4];
    const float* b_hh0    = (const float*)d_in[5];
    const float* w_ih1    = (const float*)d_in[6];
    const float* w_hh1    = (const float*)d_in[7];
    const float* b_ih1    = (const float*)d_in[8];
    const float* b_hh1    = (const float*)d_in[9];
    const float* pw1      = (const float*)d_in[10];
    const float* pb1      = (const float*)d_in[11];
    const float* pw2      = (const float*)d_in[12];
    const float* pb2      = (const float*)d_in[13];
    const float* conn_w   = (const float*)d_in[14];
    const float* sens     = (const float*)d_in[15];
    const float* thr      = (const float*)d_in[16];
    const float* iw1      = (const float*)d_in[17];
    const float* ib1      = (const float*)d_in[18];
    const float* iw2      = (const float*)d_in[19];
    const float* ib2      = (const float*)d_in[20];
    const float* iw3      = (const float*)d_in[21];
    const float* ib3      = (const float*)d_in[22];
    const float* hw_trend = (const float*)d_in[23];
    const float* hb_trend = (const float*)d_in[24];
    const float* hw_pat   = (const float*)d_in[25];
    const float* hb_pat   = (const float*)d_in[26];
    const float* hw_key   = (const float*)d_in[27];
    const float* hb_key   = (const float*)d_in[28];
    const float* hw_vol   = (const float*)d_in[29];
    const float* hb_vol   = (const float*)d_in[30];
    const float* hw_conf  = (const float*)d_in[31];
    const float* hb_conf  = (const float*)d_in[32];
    float* out = (float*)d_out;
    float* ws  = (float*)d_ws;

    // ws layout (float slots)
    unsigned short* whh0h = (unsigned short*)(ws);           // 32768 f
    unsigned short* wih1h = (unsigned short*)(ws + 32768);   // 32768 f
    unsigned short* whh1h = (unsigned short*)(ws + 65536);   // 32768 f
    float* bias0  = ws + 98304;   // 512
    float* bias1  = ws + 98816;   // 512
    // ws+99328 (old h2 slot, 131072 f) now unused — h2 stays on-chip
    float* base_  = ws + 230400;  // 32768
    float* weffT  = ws + 263168;  // 80000
    float* t1     = ws + 343168;  // 262144
    unsigned short* iw1b   = (unsigned short*)(ws + 605312); // 323584 f
    unsigned short* amatbf = (unsigned short*)(ws + 928896); // 1294336 f -> ends 2223232

    prep_all_kernel<<<2786, 256, 0, stream>>>(w_hh0, w_ih1, w_hh1,
                                              b_ih0, b_hh0, b_ih1, b_hh1, iw1,
                                              whh0h, wih1h, whh1h, bias0, bias1, iw1b);
    lstm_kernel<<<256, 512, 0, stream>>>(x, whh0h, wih1h, whh1h, w_ih0,
                                         bias0, bias1, pw1, pb1, pw2, pb2, base_);
    weff_kernel<<<20, 128, 0, stream>>>(conn_idx, conn_w, weffT);
    za_kernel<<<640, 256, 0, stream>>>(base_, weffT, sens, thr, amatbf);
    gemm_iw1_kernel<<<dim3(8, 32), 128, 0, stream>>>(amatbf, iw1b, ib1, t1);
    final_kernel<<<256, 256, 0, stream>>>(t1, amatbf, iw2, ib2, iw3, ib3,
                                          hw_trend, hb_trend, hw_pat, hb_pat,
                                          hw_key, hb_key, hw_vol, hb_vol,
                                          hw_conf, hb_conf, out);
}